// Round 14
// baseline (399.829 us; speedup 1.0000x reference)
//
#include <hip/hip_runtime.h>
#include <hip/hip_cooperative_groups.h>
#include <math.h>

namespace cg = cooperative_groups;

#define DC 8220      // dist row stride (28 + 8192)
#define OFF 28
#define NR 4096
#define NC 8192
#define INV4096 (1.0f / 4096.0f)
#define INV8192 (1.0f / 8192.0f)
#define BLK 256

#define AGENT __HIP_MEMORY_SCOPE_AGENT
typedef unsigned long long ull;

#if defined(__has_builtin)
#if __has_builtin(__builtin_amdgcn_cvt_pk_f32_fp8) && __has_builtin(__builtin_amdgcn_cvt_pk_fp8_f32)
#define HAVE_FP8_CVT 1
#endif
#endif
#ifndef HAVE_FP8_CVT
#define HAVE_FP8_CVT 0
#endif

typedef float floatx2 __attribute__((ext_vector_type(2)));

__device__ __forceinline__ float bflo(unsigned int u) { return __uint_as_float(u << 16); }
__device__ __forceinline__ float bfhi(unsigned int u) { return __uint_as_float(u & 0xffff0000u); }
__device__ __forceinline__ float bfs(unsigned short u) { return __uint_as_float(((unsigned int)u) << 16); }
__device__ __forceinline__ unsigned short f2bf(float f) {
    unsigned int i = __float_as_uint(f);
    return (unsigned short)((i + 0x7fffu + ((i >> 16) & 1u)) >> 16);   // RNE
}
__device__ __forceinline__ void st_wbf(unsigned short* p, float v) {
    __hip_atomic_store(p, f2bf(v), __ATOMIC_RELAXED, AGENT);
}
__device__ __forceinline__ float ld_wbf(const unsigned short* p) {
    unsigned short u = __hip_atomic_load(p, __ATOMIC_RELAXED, AGENT);
    return __uint_as_float(((unsigned int)u) << 16);
}

// ---------------- fp8 helpers (HW cvt or SW fallback) ----------------------
#if !HAVE_FP8_CVT
__device__ __forceinline__ float fp8dec_sw(unsigned int b) {
    unsigned int e = (b >> 3) & 0xFu, m = b & 7u;
    float mag = (e == 0) ? (float)m * 0.001953125f
                         : __uint_as_float(((e + 120u) << 23) | (m << 20));
    return (b & 0x80u) ? -mag : mag;
}
__device__ __forceinline__ unsigned int fp8enc_sw(float v) {
    if (v <= 0.0f) return 0u;
    if (v < 0.015625f) return (unsigned int)rintf(v * 512.0f) & 7u;
    int e; float fr = frexpf(v, &e);
    float q = rintf(fr * 16.0f);
    if (q >= 16.0f) { q = 8.0f; ++e; }
    return (((unsigned int)(e + 6) & 0xFu) << 3) | ((unsigned int)q & 7u);
}
#endif
__device__ __forceinline__ unsigned int pk4_fp8(float e0, float e1, float e2, float e3) {
#if HAVE_FP8_CVT
    int v = __builtin_amdgcn_cvt_pk_fp8_f32(e0, e1, 0, false);
    v = __builtin_amdgcn_cvt_pk_fp8_f32(e2, e3, v, true);
    return (unsigned int)v;
#else
    return fp8enc_sw(e0) | (fp8enc_sw(e1) << 8) | (fp8enc_sw(e2) << 16) | (fp8enc_sw(e3) << 24);
#endif
}
__device__ __forceinline__ void fp8x4_to_f32(unsigned int u, float* f) {
#if HAVE_FP8_CVT
    floatx2 p = __builtin_amdgcn_cvt_pk_f32_fp8((int)u, false);
    f[0] = p.x; f[1] = p.y;
    p = __builtin_amdgcn_cvt_pk_f32_fp8((int)u, true);
    f[2] = p.x; f[3] = p.y;
#else
    f[0] = fp8dec_sw(u & 0xffu);
    f[1] = fp8dec_sw((u >> 8) & 0xffu);
    f[2] = fp8dec_sw((u >> 16) & 0xffu);
    f[3] = fp8dec_sw((u >> 24) & 0xffu);
#endif
}

// ---- fp4 pack: 8 K-values -> one u32 of nibbles (decode-order permuted) ----
__device__ __forceinline__ unsigned int pk8_fp4(const float* e) {
    unsigned int b0 = pk4_fp8(e[0], e[1], e[2], e[3]);
    unsigned int b1 = pk4_fp8(e[4], e[5], e[6], e[7]);
    unsigned int c0 = ((b0 - 0x36363636u) >> 2) & 0x0F0F0F0Fu;
    unsigned int c1 = ((b1 - 0x36363636u) >> 2) & 0x0F0F0F0Fu;
    return c0 | (c1 << 4);
}
__device__ __forceinline__ void fp4x8_to_f32(unsigned int v, float* f) {
    unsigned int blo = ((v << 2) & 0x3C3C3C3Cu) + 0x38383838u;
    unsigned int bhi = ((v >> 2) & 0x3C3C3C3Cu) + 0x38383838u;
    fp8x4_to_f32(blo, f);
    fp8x4_to_f32(bhi, f + 4);
}

// --------------- tree grid barrier (multi-word release) --------------------
__device__ __forceinline__ void gbar(unsigned int* ctrs, unsigned int* rel,
                                     unsigned int phase, int bid, int cpl) {
    __syncthreads();
    if (threadIdx.x == 0) {
        asm volatile("s_waitcnt vmcnt(0)" ::: "memory");
        __hip_atomic_fetch_add(&ctrs[(bid & 63) * 16], 1u, __ATOMIC_RELAXED, AGENT);
    }
    if (bid == 0) {
        if (threadIdx.x < 64) {
            unsigned int tgt = phase * (unsigned int)cpl;
            while (__hip_atomic_load(&ctrs[threadIdx.x * 16], __ATOMIC_RELAXED, AGENT) < tgt)
                __builtin_amdgcn_s_sleep(1);
        }
        __syncthreads();
        if (threadIdx.x < 64)
            __hip_atomic_store(&rel[threadIdx.x * 16], phase, __ATOMIC_RELAXED, AGENT);
    } else if (threadIdx.x == 0) {
        while (__hip_atomic_load(&rel[(bid & 63) * 16], __ATOMIC_RELAXED, AGENT) < phase)
            __builtin_amdgcn_s_sleep(1);
    }
    __syncthreads();
}

// ---- LDS weight slotting: slot(c,q,l) = c*256 + q*64 + l ------------------
__device__ __forceinline__ int slot4(int g8) {
    return ((g8 >> 8) << 8) + (g8 & 3) * 64 + ((g8 >> 2) & 63);
}

// stage wQ (8192 bf16 -> slots [0,1024)) and wP (4096 -> slots [1024,1536))
__device__ __forceinline__ void stage2(const unsigned short* __restrict__ wQ,
                                       const unsigned short* __restrict__ wP,
                                       ull* lds, int tid) {
    uint4* lds4 = (uint4*)lds;
    for (int g8 = tid; g8 < 1024; g8 += BLK) {
        ull v0 = __hip_atomic_load((const ull*)wQ + 2 * g8, __ATOMIC_RELAXED, AGENT);
        ull v1 = __hip_atomic_load((const ull*)wQ + 2 * g8 + 1, __ATOMIC_RELAXED, AGENT);
        lds4[slot4(g8)] = make_uint4((unsigned int)v0, (unsigned int)(v0 >> 32),
                                     (unsigned int)v1, (unsigned int)(v1 >> 32));
    }
    for (int g8 = tid; g8 < 512; g8 += BLK) {
        ull v0 = __hip_atomic_load((const ull*)wP + 2 * g8, __ATOMIC_RELAXED, AGENT);
        ull v1 = __hip_atomic_load((const ull*)wP + 2 * g8 + 1, __ATOMIC_RELAXED, AGENT);
        lds4[1024 + slot4(g8)] = make_uint4((unsigned int)v0, (unsigned int)(v0 >> 32),
                                            (unsigned int)v1, (unsigned int)(v1 >> 32));
    }
    __syncthreads();
}

// fused tiled builder: one 64x64 dist tile -> M1,M2T (row-major) + MT1,MT2 (T)
__device__ __forceinline__ void build_tile4(const float* __restrict__ dist,
                                            const float* __restrict__ rm1,
                                            const float* __restrict__ d12,
                                            unsigned char* __restrict__ M1,
                                            unsigned char* __restrict__ MT1,
                                            unsigned char* __restrict__ M2T,
                                            unsigned char* __restrict__ MT2,
                                            float (*tl)[65], float* rms, float* d12s,
                                            int t, int tid) {
    int i0 = (t >> 7) * 64;
    int j0 = (t & 127) * 64;
    int r = tid >> 2, cq = (tid & 3) * 16;
    {
        const float* Dr = dist + (size_t)(i0 + r) * DC + OFF + j0 + cq;
        float4 v0 = *(const float4*)Dr;
        float4 v1 = *(const float4*)(Dr + 4);
        float4 v2 = *(const float4*)(Dr + 8);
        float4 v3 = *(const float4*)(Dr + 12);
        *(float4*)&tl[r][cq + 0]  = v0;
        *(float4*)&tl[r][cq + 4]  = v1;
        *(float4*)&tl[r][cq + 8]  = v2;
        *(float4*)&tl[r][cq + 12] = v3;
        if (tid < 64) { rms[tid] = rm1[i0 + tid]; d12s[tid] = d12[j0 + tid]; }
    }
    __syncthreads();
    {   // row-major: M1[i][j], M2T[i][j]
        float rm = rms[r];
        int iglob = i0 + r;
        float k1[16], k2[16];
#pragma unroll
        for (int k = 0; k < 16; ++k) {
            int jglob = j0 + cq + k;
            float dvv = tl[r][cq + k];
            bool dg1 = (jglob == iglob) || (jglob == iglob + 4096);
            float g1 = dg1 ? 0.0f : fmaxf(0.05f + dvv - rm, 0.0f);
            k1[k] = __expf(5.0f * __expf(-g1));
            bool dg2 = (iglob == (jglob & 4095));
            float g2 = dg2 ? 0.0f : fmaxf(0.05f + dvv - d12s[cq + k], 0.0f);
            k2[k] = __expf(5.0f * __expf(-g2));
        }
        uint2 o1, o2;
        o1.x = pk8_fp4(k1); o1.y = pk8_fp4(k1 + 8);
        o2.x = pk8_fp4(k2); o2.y = pk8_fp4(k2 + 8);
        *(uint2*)(M1 + (size_t)iglob * 4096 + ((j0 + cq) >> 1)) = o1;
        *(uint2*)(M2T + (size_t)iglob * 4096 + ((j0 + cq) >> 1)) = o2;
    }
    {   // transposed: MT1[j][i], MT2[j][i]
        int jj = r;
        int jglob = j0 + jj;
        float dd = d12s[jj];
        float k1[16], k2[16];
#pragma unroll
        for (int k = 0; k < 16; ++k) {
            int iglob = i0 + cq + k;
            float dvv = tl[cq + k][jj];
            bool dg1 = (jglob == iglob) || (jglob == iglob + 4096);
            float g1 = dg1 ? 0.0f : fmaxf(0.05f + dvv - rms[cq + k], 0.0f);
            k1[k] = __expf(5.0f * __expf(-g1));
            bool dg2 = (iglob == (jglob & 4095));
            float g2 = dg2 ? 0.0f : fmaxf(0.05f + dvv - dd, 0.0f);
            k2[k] = __expf(5.0f * __expf(-g2));
        }
        uint2 o1, o2;
        o1.x = pk8_fp4(k1); o1.y = pk8_fp4(k1 + 8);
        o2.x = pk8_fp4(k2); o2.y = pk8_fp4(k2 + 8);
        *(uint2*)(MT1 + (size_t)jglob * 2048 + ((i0 + cq) >> 1)) = o1;
        *(uint2*)(MT2 + (size_t)jglob * 2048 + ((i0 + cq) >> 1)) = o2;
    }
    __syncthreads();
}

// ------------------------- cooperative dual-loss kernel --------------------
__global__ __launch_bounds__(BLK, 4) void k_main(const float* __restrict__ dist,
                                                 float* __restrict__ out,
                                                 unsigned char* __restrict__ M1,
                                                 unsigned char* __restrict__ MT1,
                                                 unsigned char* __restrict__ M2T,
                                                 unsigned char* __restrict__ MT2,
                                                 unsigned short* __restrict__ w_c1,
                                                 unsigned short* __restrict__ w_c2,
                                                 unsigned short* __restrict__ w_r1,
                                                 unsigned short* __restrict__ w_r2,
                                                 float* __restrict__ rm1,
                                                 int* __restrict__ arg1,
                                                 float* __restrict__ d12,
                                                 float* __restrict__ numb,
                                                 float* __restrict__ denb,
                                                 float* __restrict__ num1,
                                                 float* __restrict__ den1,
                                                 unsigned int* __restrict__ ctrs,
                                                 unsigned int* __restrict__ rel,
                                                 unsigned int* __restrict__ flags) {
    cg::grid_group grid = cg::this_grid();
    const int tid = threadIdx.x, bid = blockIdx.x;
    const int nb = gridDim.x, nt = nb * BLK;
    const int gt = bid * BLK + tid;
    const int nw = nt >> 6, wave = gt >> 6, lane = tid & 63;
    const int cpl = nb >> 6;
    unsigned int pc = 0;

    extern __shared__ char smem[];                // 24832 B
    ull* lds64 = (ull*)smem;
    const uint4* vv4 = (const uint4*)smem;
    float (*tl)[65] = (float(*)[65])smem;
    float* rms  = (float*)(smem + 16640);
    float* d12s = (float*)(smem + 16896);
    // epilogue overlays
    float* wsm  = (float*)smem;                   // 32
    float* rms2 = (float*)(smem + 128);           // 32
    int*  args2 = (int*)(smem + 256);             // 32
    float* n1s  = (float*)(smem + 384);           // 32
    float* d1s  = (float*)(smem + 512);           // 32
    int* chflag = (int*)(smem + 24576);
    int* convfl = (int*)(smem + 24580);

    // ---------------- init ----------------
    for (int t = gt; t < NC; t += nt) {
        if (t == 0) __hip_atomic_store(out, 0.0f, __ATOMIC_RELAXED, AGENT);
        if (t < NR) {
            float a = dist[(size_t)t * DC + OFF + t];
            float b = dist[(size_t)t * DC + OFF + 4096 + t];
            rm1[t] = fmaxf(a, b);
            arg1[t] = (a >= b) ? t : t + 4096;
            st_wbf(&w_r1[t], INV4096);            // u1_0
            __hip_atomic_store(&num1[t], 0.0f, __ATOMIC_RELAXED, AGENT);
            __hip_atomic_store(&den1[t], 0.0f, __ATOMIC_RELAXED, AGENT);
        }
        d12[t] = dist[(size_t)(t & 4095) * DC + OFF + t];
        st_wbf(&w_c2[t], INV8192);                // u2_0
        __hip_atomic_store(&numb[t], 0.0f, __ATOMIC_RELAXED, AGENT);
        __hip_atomic_store(&denb[t], 0.0f, __ATOMIC_RELAXED, AGENT);
    }
    grid.sync();
    for (int t = bid; t < 8192; t += nb)
        build_tile4(dist, rm1, d12, M1, MT1, M2T, MT2, tl, rms, d12s, t, tid);
    grid.sync();

    // ------- interleaved Sinkhorn: <=99 phases, 1-ulp fixed-point exit ------
    // Q-row and P-row-pair merged per r: all 8 global loads issue up-front.
    for (int t = 0; t < 99; ++t) {
        bool ph1 = ((t & 1) == 0);
        const unsigned char* P = ph1 ? MT1 : MT2;   // 8192 x 4096 (2048 B rows)
        const unsigned char* Q = ph1 ? M2T : M1;    // 4096 x 8192 (4096 B rows)
        const unsigned short* wPs = ph1 ? w_r1 : w_r2;
        const unsigned short* wQs = ph1 ? w_c2 : w_c1;
        unsigned short* Pout = ph1 ? w_c1 : w_c2;
        unsigned short* Qout = ph1 ? w_r2 : w_r1;
        if (tid == 0) *chflag = 0;
        stage2(wQs, wPs, lds64, tid);               // ends with __syncthreads
        for (int r = wave; r < NR; r += nw) {
            const unsigned char* qrow = Q + (size_t)r * 4096;
            const unsigned char* p0 = P + (size_t)r * 2048;
            const unsigned char* p1 = P + (size_t)(r + 4096) * 2048;
            // ---- MLP burst: 8 x uint4 global loads ----
            uint4 qa[4], pa[2], pb[2];
#pragma unroll
            for (int c = 0; c < 4; ++c)
                qa[c] = *(const uint4*)(qrow + c * 1024 + lane * 16);
#pragma unroll
            for (int c = 0; c < 2; ++c) {
                pa[c] = *(const uint4*)(p0 + c * 1024 + lane * 16);
                pb[c] = *(const uint4*)(p1 + c * 1024 + lane * 16);
            }
            // ---- Q decode/FMA (same order as round-13 dotQ4) ----
            float acc = 0.0f;
#pragma unroll
            for (int c = 0; c < 4; ++c) {
                unsigned int vs[4] = {qa[c].x, qa[c].y, qa[c].z, qa[c].w};
#pragma unroll
                for (int q = 0; q < 4; ++q) {
                    float f[8];
                    fp4x8_to_f32(vs[q], f);
                    uint4 w = vv4[c * 256 + q * 64 + lane];
                    acc = fmaf(f[0], bflo(w.x), acc); acc = fmaf(f[1], bfhi(w.x), acc);
                    acc = fmaf(f[2], bflo(w.y), acc); acc = fmaf(f[3], bfhi(w.y), acc);
                    acc = fmaf(f[4], bflo(w.z), acc); acc = fmaf(f[5], bfhi(w.z), acc);
                    acc = fmaf(f[6], bflo(w.w), acc); acc = fmaf(f[7], bfhi(w.w), acc);
                }
            }
            // ---- P pair decode/FMA (same order as round-13 dotP24) ----
            float a0 = 0.0f, a1 = 0.0f;
#pragma unroll
            for (int c = 0; c < 2; ++c) {
                unsigned int va[4] = {pa[c].x, pa[c].y, pa[c].z, pa[c].w};
                unsigned int vb[4] = {pb[c].x, pb[c].y, pb[c].z, pb[c].w};
#pragma unroll
                for (int q = 0; q < 4; ++q) {
                    float fa[8], fb[8];
                    fp4x8_to_f32(va[q], fa);
                    fp4x8_to_f32(vb[q], fb);
                    uint4 w = vv4[1024 + c * 256 + q * 64 + lane];
                    float wv[8] = {bflo(w.x), bfhi(w.x), bflo(w.y), bfhi(w.y),
                                   bflo(w.z), bfhi(w.z), bflo(w.w), bfhi(w.w)};
#pragma unroll
                    for (int e = 0; e < 8; ++e) {
                        a0 = fmaf(fa[e], wv[e], a0);
                        a1 = fmaf(fb[e], wv[e], a1);
                    }
                }
            }
            // ---- fused 3-value wave reduce (per-value order unchanged) ----
#pragma unroll
            for (int o = 32; o; o >>= 1) {
                acc += __shfl_down(acc, o);
                a0 += __shfl_down(a0, o);
                a1 += __shfl_down(a1, o);
            }
            if (lane == 0) {
                unsigned short nq = f2bf(__fdividef(INV4096, acc));
                unsigned short n0 = f2bf(__fdividef(INV8192, a0));
                unsigned short n1 = f2bf(__fdividef(INV8192, a1));
                unsigned short oq = __hip_atomic_load(&Qout[r], __ATOMIC_RELAXED, AGENT);
                unsigned short o0 = __hip_atomic_load(&Pout[r], __ATOMIC_RELAXED, AGENT);
                unsigned short o1 = __hip_atomic_load(&Pout[r + 4096], __ATOMIC_RELAXED, AGENT);
                int dq = (int)nq - (int)oq;
                int d0i = (int)n0 - (int)o0;
                int d1i = (int)n1 - (int)o1;
                if (dq > 1 || dq < -1 || d0i > 1 || d0i < -1 || d1i > 1 || d1i < -1)
                    *chflag = 1;
                __hip_atomic_store(&Qout[r], nq, __ATOMIC_RELAXED, AGENT);
                __hip_atomic_store(&Pout[r], n0, __ATOMIC_RELAXED, AGENT);
                __hip_atomic_store(&Pout[r + 4096], n1, __ATOMIC_RELAXED, AGENT);
            }
        }
        __syncthreads();
        if (tid == 0 && *chflag)
            __hip_atomic_store(&flags[t], 1u, __ATOMIC_RELAXED, AGENT);  // before arrival
        gbar(ctrs, rel, ++pc, bid, cpl);
        if (tid == 0)
            *convfl = (int)__hip_atomic_load(&flags[t], __ATOMIC_RELAXED, AGENT);
        __syncthreads();
        if (*convfl == 0) break;                    // <=1-ulp fixed point: stop
    }

    // ---------------- fused epilogue: one dist pass, both losses ----------
    for (int t2 = bid; t2 < 1024; t2 += nb) {
        int r0 = (t2 >> 3) * 32;
        int c = (t2 & 7) * 1024 + tid * 4;
        if (tid < 32) {
            wsm[tid]  = ld_wbf(&w_r2[r0 + tid]);
            rms2[tid] = rm1[r0 + tid];
            args2[tid] = arg1[r0 + tid];
            n1s[tid] = 0.0f; d1s[tid] = 0.0f;
        }
        __syncthreads();
        ull wcu = __hip_atomic_load((const ull*)w_c1 + (c >> 2), __ATOMIC_RELAXED, AGENT);
        float wc1v[4] = {bfs((unsigned short)wcu), bfs((unsigned short)(wcu >> 16)),
                         bfs((unsigned short)(wcu >> 32)), bfs((unsigned short)(wcu >> 48))};
        float4 e0 = *(const float4*)(d12 + c);
        float dd[4] = {e0.x, e0.y, e0.z, e0.w};
        float nacc2[4] = {0.f, 0.f, 0.f, 0.f};
        float dacc2[4] = {0.f, 0.f, 0.f, 0.f};
        for (int r = 0; r < 32; ++r) {
            int rr = r0 + r;
            float rm = rms2[r];
            int arg = args2[r];
            float ww = wsm[r];
            float4 dv4 = *(const float4*)(dist + (size_t)rr * DC + OFF + c);
            float dv[4] = {dv4.x, dv4.y, dv4.z, dv4.w};
            float n1t = 0.0f, d1t = 0.0f;
#pragma unroll
            for (int e = 0; e < 4; ++e) {
                int cc = c + e;
                float d = dv[e];
                float gm2 = fmaxf(0.05f + d - dd[e], 0.0f);
                float K2 = __expf(5.0f * __expf(-gm2));
                float wv2 = (rr == (cc & 4095)) ? 0.0f : K2 * ww;
                nacc2[e] += wv2 * gm2;
                dacc2[e] += wv2;
                bool isd1 = (cc == rr) || (cc == rr + 4096);
                float goff = fmaxf(0.05f + d - rm, 0.0f);
                float K1 = __expf(5.0f * __expf(-(isd1 ? 0.0f : goff)));
                float gm1 = isd1 ? fmaxf(rm - 0.5f - d, 0.0f) : goff;
                bool keep = (cc != arg) && ((cc < 4096) || (cc == rr + 4096));
                float wv1 = keep ? K1 * wc1v[e] : 0.0f;
                n1t += wv1 * gm1;
                d1t += wv1;
            }
#pragma unroll
            for (int o = 32; o; o >>= 1) {
                n1t += __shfl_down(n1t, o);
                d1t += __shfl_down(d1t, o);
            }
            if (lane == 0) {
                atomicAdd(&n1s[r], n1t);
                atomicAdd(&d1s[r], d1t);
            }
        }
        __syncthreads();
#pragma unroll
        for (int e = 0; e < 4; ++e) {
            atomicAdd(&numb[c + e], nacc2[e]);
            atomicAdd(&denb[c + e], dacc2[e]);
        }
        if (tid < 32) {
            atomicAdd(&num1[r0 + tid], n1s[tid]);
            atomicAdd(&den1[r0 + tid], d1s[tid]);
        }
        __syncthreads();
    }
    gbar(ctrs, rel, ++pc, bid, cpl);

    // ---------------- final reduce: loss2 (128 groups) + loss1 (64 groups) --
    for (int t2 = wave; t2 < 192; t2 += nw) {
        float v;
        if (t2 < 128) {
            int cc = t2 * 64 + lane;
            float n = __hip_atomic_load(&numb[cc], __ATOMIC_RELAXED, AGENT);
            float dn = __hip_atomic_load(&denb[cc], __ATOMIC_RELAXED, AGENT);
            v = n / dn;
        } else {
            int ii = (t2 - 128) * 64 + lane;
            float n = __hip_atomic_load(&num1[ii], __ATOMIC_RELAXED, AGENT);
            float dn = __hip_atomic_load(&den1[ii], __ATOMIC_RELAXED, AGENT);
            v = n / dn;
        }
#pragma unroll
        for (int o = 32; o; o >>= 1) v += __shfl_down(v, o);
        if (lane == 0) atomicAdd(out, v);
    }
}

// ------------------------- fallback multi-kernel path (bf16, proven) -------
__device__ __forceinline__ void fb_build1(const float* __restrict__ dist,
                                          const float* __restrict__ rm1,
                                          unsigned short* __restrict__ M, int c) {
    int i = c >> 10;
    int j = (c & 1023) << 3;
    float rm = rm1[i];
    const float* Dr = dist + (size_t)i * DC + OFF + j;
    float4 d0 = *(const float4*)Dr;
    float4 d1 = *(const float4*)(Dr + 4);
    float dv[8] = {d0.x, d0.y, d0.z, d0.w, d1.x, d1.y, d1.z, d1.w};
    unsigned short e[8];
#pragma unroll
    for (int k = 0; k < 8; ++k) {
        int jj = j + k;
        bool diag = (jj == i) || (jj == i + 4096);
        float gm = diag ? 0.0f : fmaxf(0.05f + dv[k] - rm, 0.0f);
        e[k] = f2bf(__expf(5.0f * __expf(-gm)));
    }
    uint4 o;
    o.x = (unsigned int)e[0] | ((unsigned int)e[1] << 16);
    o.y = (unsigned int)e[2] | ((unsigned int)e[3] << 16);
    o.z = (unsigned int)e[4] | ((unsigned int)e[5] << 16);
    o.w = (unsigned int)e[6] | ((unsigned int)e[7] << 16);
    *(uint4*)(M + (size_t)c * 8) = o;
}
__device__ __forceinline__ void fb_build2(const float* __restrict__ dist,
                                          const float* __restrict__ d12,
                                          unsigned short* __restrict__ M, int c) {
    int r = c >> 10;
    int col = (c & 1023) << 3;
    const float* Dr = dist + (size_t)r * DC + OFF + col;
    float4 d0 = *(const float4*)Dr;
    float4 d1 = *(const float4*)(Dr + 4);
    float4 e0 = *(const float4*)(d12 + col);
    float4 e1 = *(const float4*)(d12 + col + 4);
    float dv[8] = {d0.x, d0.y, d0.z, d0.w, d1.x, d1.y, d1.z, d1.w};
    float dd[8] = {e0.x, e0.y, e0.z, e0.w, e1.x, e1.y, e1.z, e1.w};
    unsigned short e[8];
#pragma unroll
    for (int k = 0; k < 8; ++k) {
        int cc = col + k;
        bool diag = (r == (cc & 4095));
        float gm = diag ? 0.0f : fmaxf(0.05f + dv[k] - dd[k], 0.0f);
        e[k] = f2bf(__expf(5.0f * __expf(-gm)));
    }
    uint4 o;
    o.x = (unsigned int)e[0] | ((unsigned int)e[1] << 16);
    o.y = (unsigned int)e[2] | ((unsigned int)e[3] << 16);
    o.z = (unsigned int)e[4] | ((unsigned int)e[5] << 16);
    o.w = (unsigned int)e[6] | ((unsigned int)e[7] << 16);
    *(uint4*)(M + (size_t)c * 8) = o;
}
__device__ __forceinline__ void fb_transpose(const unsigned short* __restrict__ M,
                                             unsigned short* __restrict__ MT,
                                             unsigned int (*tile)[33], int t, int tid) {
    int r0 = (t >> 7) * 64;
    int c0 = (t & 127) * 64;
    int lc = tid & 7, rr = tid >> 3;
#pragma unroll
    for (int s = 0; s < 2; ++s) {
        int r = rr + s * 32;
        uint4 a = *(const uint4*)(M + (size_t)(r0 + r) * NC + c0 + lc * 8);
        tile[r][lc * 4 + 0] = a.x;
        tile[r][lc * 4 + 1] = a.y;
        tile[r][lc * 4 + 2] = a.z;
        tile[r][lc * 4 + 3] = a.w;
    }
    __syncthreads();
    int cc = tid >> 2, rs = (tid & 3) * 16;
    unsigned int o[8];
#pragma unroll
    for (int w = 0; w < 8; ++w) {
        unsigned int ue = tile[rs + 2 * w][cc >> 1];
        unsigned int uo = tile[rs + 2 * w + 1][cc >> 1];
        unsigned short e = (cc & 1) ? (unsigned short)(ue >> 16) : (unsigned short)(ue & 0xffffu);
        unsigned short d = (cc & 1) ? (unsigned short)(uo >> 16) : (unsigned short)(uo & 0xffffu);
        o[w] = (unsigned int)e | ((unsigned int)d << 16);
    }
    unsigned short* dst = MT + (size_t)(c0 + cc) * NR + r0 + rs;
    *(uint4*)dst = make_uint4(o[0], o[1], o[2], o[3]);
    *(uint4*)(dst + 8) = make_uint4(o[4], o[5], o[6], o[7]);
    __syncthreads();
}
template <int W>
__device__ __forceinline__ float rowdot_g(const unsigned short* __restrict__ row,
                                          const float* __restrict__ w, int lane) {
    float acc = 0.0f;
#pragma unroll
    for (int s = 0; s < W; s += 512) {
        int j = s + lane * 8;
        uint4 a = *(const uint4*)(row + j);
        float4 w0 = *(const float4*)(w + j);
        float4 w1 = *(const float4*)(w + j + 4);
        acc = fmaf(bflo(a.x), w0.x, acc);
        acc = fmaf(bfhi(a.x), w0.y, acc);
        acc = fmaf(bflo(a.y), w0.z, acc);
        acc = fmaf(bfhi(a.y), w0.w, acc);
        acc = fmaf(bflo(a.z), w1.x, acc);
        acc = fmaf(bfhi(a.z), w1.y, acc);
        acc = fmaf(bflo(a.w), w1.z, acc);
        acc = fmaf(bfhi(a.w), w1.w, acc);
    }
#pragma unroll
    for (int o = 32; o; o >>= 1) acc += __shfl_down(acc, o);
    return acc;
}
__global__ __launch_bounds__(BLK) void k_fb_init(const float* __restrict__ dist,
                                                 float* __restrict__ rm1, int* __restrict__ arg1,
                                                 float* __restrict__ d12, float* __restrict__ wrow,
                                                 float* __restrict__ out) {
    int t = blockIdx.x * BLK + threadIdx.x;
    if (t == 0) out[0] = 0.0f;
    if (t < NR) {
        float a = dist[(size_t)t * DC + OFF + t];
        float b = dist[(size_t)t * DC + OFF + 4096 + t];
        rm1[t] = fmaxf(a, b);
        arg1[t] = (a >= b) ? t : t + 4096;
        wrow[t] = INV4096;
    }
    d12[t] = dist[(size_t)(t & 4095) * DC + OFF + t];
}
__global__ __launch_bounds__(BLK) void k_fb_build1(const float* __restrict__ dist,
                                                   const float* __restrict__ rm1,
                                                   unsigned short* __restrict__ M) {
    fb_build1(dist, rm1, M, blockIdx.x * BLK + threadIdx.x);
}
__global__ __launch_bounds__(BLK) void k_fb_build2(const float* __restrict__ dist,
                                                   const float* __restrict__ d12,
                                                   unsigned short* __restrict__ M) {
    fb_build2(dist, d12, M, blockIdx.x * BLK + threadIdx.x);
}
__global__ __launch_bounds__(BLK) void k_fb_transp(const unsigned short* __restrict__ M,
                                                   unsigned short* __restrict__ MT) {
    __shared__ unsigned int tile[64][33];
    fb_transpose(M, MT, tile, blockIdx.x, threadIdx.x);
}
template <int W>
__global__ __launch_bounds__(BLK) void k_fb_matvec(const unsigned short* __restrict__ Mat,
                                                   const float* __restrict__ w,
                                                   float* __restrict__ outv, float scale) {
    int r = blockIdx.x * 4 + (threadIdx.x >> 6);
    float s = rowdot_g<W>(Mat + (size_t)r * W, w, threadIdx.x & 63);
    if ((threadIdx.x & 63) == 0) outv[r] = __fdividef(scale, s);
}
__global__ __launch_bounds__(BLK) void k_fb_epi1(const unsigned short* __restrict__ M,
                                                 const float* __restrict__ dist,
                                                 const float* __restrict__ wcol,
                                                 const float* __restrict__ rm1,
                                                 const int* __restrict__ arg1,
                                                 float* __restrict__ out) {
    int i = blockIdx.x * 4 + (threadIdx.x >> 6);
    int lane = threadIdx.x & 63;
    float rm = rm1[i];
    int arg = arg1[i];
    const unsigned short* Ar = M + (size_t)i * NC;
    const float* Dr = dist + (size_t)i * DC + OFF;
    float num = 0.0f, den = 0.0f;
#pragma unroll 4
    for (int s = 0; s < NC; s += 512) {
        int j0 = s + lane * 8;
        uint4 a = *(const uint4*)(Ar + j0);
        float4 t0 = *(const float4*)(wcol + j0);
        float4 t1 = *(const float4*)(wcol + j0 + 4);
        float4 d0 = *(const float4*)(Dr + j0);
        float4 d1 = *(const float4*)(Dr + j0 + 4);
        float av[8] = {bflo(a.x), bfhi(a.x), bflo(a.y), bfhi(a.y),
                       bflo(a.z), bfhi(a.z), bflo(a.w), bfhi(a.w)};
        float tv[8] = {t0.x, t0.y, t0.z, t0.w, t1.x, t1.y, t1.z, t1.w};
        float dv[8] = {d0.x, d0.y, d0.z, d0.w, d1.x, d1.y, d1.z, d1.w};
#pragma unroll
        for (int e = 0; e < 8; ++e) {
            int jj = j0 + e;
            bool isdiag = (jj == i) || (jj == i + 4096);
            float gm = isdiag ? fmaxf(rm - 0.5f - dv[e], 0.0f)
                              : fmaxf(0.05f + dv[e] - rm, 0.0f);
            bool keep = (jj != arg) && ((jj < 4096) || (jj == i + 4096));
            float wv = keep ? av[e] * tv[e] : 0.0f;
            num += wv * gm;
            den += wv;
        }
    }
#pragma unroll
    for (int o = 32; o; o >>= 1) {
        num += __shfl_down(num, o);
        den += __shfl_down(den, o);
    }
    if (lane == 0) atomicAdd(out, num / den);
}
__global__ __launch_bounds__(BLK) void k_fb_init2(float* __restrict__ wcol,
                                                  float* __restrict__ numb,
                                                  float* __restrict__ denb) {
    int t = blockIdx.x * BLK + threadIdx.x;
    wcol[t] = INV8192;
    numb[t] = 0.0f;
    denb[t] = 0.0f;
}
__global__ __launch_bounds__(BLK) void k_fb_epi2(const unsigned short* __restrict__ M,
                                                 const float* __restrict__ dist,
                                                 const float* __restrict__ wrow,
                                                 const float* __restrict__ d12,
                                                 float* __restrict__ numb,
                                                 float* __restrict__ denb) {
    __shared__ float wsm[64];
    int t = blockIdx.x, tid = threadIdx.x;
    int r0 = (t >> 3) * 64;
    int c = (t & 7) * 1024 + tid * 4;
    if (tid < 64) wsm[tid] = wrow[r0 + tid];
    __syncthreads();
    float4 e0 = *(const float4*)(d12 + c);
    float dd[4] = {e0.x, e0.y, e0.z, e0.w};
    float nacc[4] = {0.f, 0.f, 0.f, 0.f};
    float dacc[4] = {0.f, 0.f, 0.f, 0.f};
    for (int r = 0; r < 64; ++r) {
        int rr = r0 + r;
        uint2 a = *(const uint2*)(M + (size_t)rr * NC + c);
        float4 dv4 = *(const float4*)(dist + (size_t)rr * DC + OFF + c);
        float av[4] = {bflo(a.x), bfhi(a.x), bflo(a.y), bfhi(a.y)};
        float dv[4] = {dv4.x, dv4.y, dv4.z, dv4.w};
        float ww = wsm[r];
#pragma unroll
        for (int e = 0; e < 4; ++e) {
            int cc = c + e;
            bool isdiag = (rr == (cc & 4095));
            float gm = fmaxf(0.05f + dv[e] - dd[e], 0.0f);
            float wv = isdiag ? 0.0f : av[e] * ww;
            nacc[e] += wv * gm;
            dacc[e] += wv;
        }
    }
#pragma unroll
    for (int e = 0; e < 4; ++e) {
        atomicAdd(&numb[c + e], nacc[e]);
        atomicAdd(&denb[c + e], dacc[e]);
    }
}
__global__ __launch_bounds__(BLK) void k_fb_epi2fin(const float* __restrict__ numb,
                                                    const float* __restrict__ denb,
                                                    float* __restrict__ out) {
    int c = blockIdx.x * BLK + threadIdx.x;
    float v = numb[c] / denb[c];
    __shared__ float sm[4];
#pragma unroll
    for (int o = 32; o; o >>= 1) v += __shfl_down(v, o);
    if ((threadIdx.x & 63) == 0) sm[threadIdx.x >> 6] = v;
    __syncthreads();
    if (threadIdx.x == 0) atomicAdd(out, sm[0] + sm[1] + sm[2] + sm[3]);
}

// ---------------------------------------------------------------------------
extern "C" void kernel_launch(void* const* d_in, const int* in_sizes, int n_in,
                              void* d_out, int out_size, void* d_ws, size_t ws_size,
                              hipStream_t stream) {
    const float* dist = (const float*)d_in[0];
    float* out = (float*)d_out;

    const size_t MB32 = (size_t)NR * NC;          // elems per matrix
    const size_t MB4  = MB32 / 2;                 // fp4 bytes per matrix
    unsigned char* M1  = (unsigned char*)d_ws;
    unsigned char* MT1 = M1 + MB4;
    unsigned char* M2T = MT1 + MB4;
    unsigned char* MT2 = M2T + MB4;               // 67 MB total (L3-resident)
    unsigned short* Mfb  = (unsigned short*)d_ws; // fallback overlay
    unsigned short* MTfb = Mfb + MB32;
    // aux beyond 134 MB
    unsigned short* w_c1 = (unsigned short*)((char*)d_ws + 4 * MB32);
    unsigned short* w_c2 = w_c1 + NC;
    unsigned short* w_r1 = w_c2 + NC;
    unsigned short* w_r2 = w_r1 + NR;
    float* fbf   = (float*)(w_r2 + NR);
    float* wrowF = fbf;
    float* wcolF = wrowF + NR;
    float* rm1  = wcolF + NC;
    int*   arg1 = (int*)(rm1 + NR);
    float* d12  = (float*)(arg1 + NR);
    float* numb = d12 + NC;
    float* denb = numb + NC;
    float* num1 = denb + NC;
    float* den1 = num1 + NR;
    unsigned int* ctrs  = (unsigned int*)(den1 + NR);  // 64*16
    unsigned int* rel   = ctrs + 64 * 16;              // 64*16
    unsigned int* flags = rel + 64 * 16;               // 128

    const unsigned int SMEM = 24832;

    int dev = 0;
    (void)hipGetDevice(&dev);
    int numCU = 0;
    (void)hipDeviceGetAttribute(&numCU, hipDeviceAttributeMultiprocessorCount, dev);
    int maxPerCU = 0;
    (void)hipOccupancyMaxActiveBlocksPerMultiprocessor(&maxPerCU, (const void*)k_main,
                                                       BLK, SMEM);
    hipError_t rc = hipErrorUnknown;
    int cand = (numCU > 0 && maxPerCU > 0) ? maxPerCU * numCU : 0;
    if (cand > 1024) cand = 1024;
    int grid = 0;
    if (cand >= 128) { grid = 128; while (grid * 2 <= cand) grid *= 2; }
    if (grid > 0) {
        (void)hipMemsetAsync(ctrs, 0, (64 * 16 * 2 + 128) * sizeof(unsigned int), stream);
        void* args[] = {(void*)&dist, (void*)&out, (void*)&M1, (void*)&MT1,
                        (void*)&M2T, (void*)&MT2,
                        (void*)&w_c1, (void*)&w_c2, (void*)&w_r1, (void*)&w_r2,
                        (void*)&rm1, (void*)&arg1, (void*)&d12,
                        (void*)&numb, (void*)&denb, (void*)&num1, (void*)&den1,
                        (void*)&ctrs, (void*)&rel, (void*)&flags};
        for (int g = grid; g >= 128 && rc != hipSuccess; g >>= 1) {
            rc = hipLaunchCooperativeKernel((void*)k_main, dim3(g), dim3(BLK),
                                            args, SMEM, stream);
            if (rc != hipSuccess) (void)hipGetLastError();
        }
    }
    if (rc == hipSuccess) return;

    // ---- fallback: multi-kernel graph path (guaranteed) ----
    k_fb_init<<<32, BLK, 0, stream>>>(dist, rm1, arg1, d12, wrowF, out);
    k_fb_build1<<<16384, BLK, 0, stream>>>(dist, rm1, Mfb);
    k_fb_transp<<<8192, BLK, 0, stream>>>(Mfb, MTfb);
    for (int it = 0; it < 50; ++it) {
        k_fb_matvec<NR><<<2048, BLK, 0, stream>>>(MTfb, wrowF, wcolF, INV8192);
        if (it == 49) break;
        k_fb_matvec<NC><<<1024, BLK, 0, stream>>>(Mfb, wcolF, wrowF, INV4096);
    }
    k_fb_epi1<<<1024, BLK, 0, stream>>>(Mfb, dist, wcolF, rm1, arg1, out);

    k_fb_build2<<<16384, BLK, 0, stream>>>(dist, d12, Mfb);
    k_fb_init2<<<32, BLK, 0, stream>>>(wcolF, numb, denb);
    k_fb_transp<<<8192, BLK, 0, stream>>>(Mfb, MTfb);
    for (int it = 0; it < 50; ++it) {
        k_fb_matvec<NC><<<1024, BLK, 0, stream>>>(Mfb, wcolF, wrowF, INV4096);
        if (it == 49) break;
        k_fb_matvec<NR><<<2048, BLK, 0, stream>>>(MTfb, wrowF, wcolF, INV8192);
    }
    k_fb_epi2<<<512, BLK, 0, stream>>>(Mfb, dist, wrowF, d12, numb, denb);
    k_fb_epi2fin<<<32, BLK, 0, stream>>>(numb, denb, out);
}

// Round 15
// 388.659 us; speedup vs baseline: 1.0287x; 1.0287x over previous
//
#include <hip/hip_runtime.h>
#include <hip/hip_cooperative_groups.h>
#include <math.h>

namespace cg = cooperative_groups;

#define DC 8220      // dist row stride (28 + 8192)
#define OFF 28
#define NR 4096
#define NC 8192
#define INV4096 (1.0f / 4096.0f)
#define INV8192 (1.0f / 8192.0f)
#define BLK 256

#define AGENT __HIP_MEMORY_SCOPE_AGENT
typedef unsigned long long ull;

#if defined(__has_builtin)
#if __has_builtin(__builtin_amdgcn_cvt_pk_f32_fp8) && __has_builtin(__builtin_amdgcn_cvt_pk_fp8_f32)
#define HAVE_FP8_CVT 1
#endif
#endif
#ifndef HAVE_FP8_CVT
#define HAVE_FP8_CVT 0
#endif

typedef float floatx2 __attribute__((ext_vector_type(2)));

__device__ __forceinline__ float bflo(unsigned int u) { return __uint_as_float(u << 16); }
__device__ __forceinline__ float bfhi(unsigned int u) { return __uint_as_float(u & 0xffff0000u); }
__device__ __forceinline__ float bfs(unsigned short u) { return __uint_as_float(((unsigned int)u) << 16); }
__device__ __forceinline__ unsigned short f2bf(float f) {
    unsigned int i = __float_as_uint(f);
    return (unsigned short)((i + 0x7fffu + ((i >> 16) & 1u)) >> 16);   // RNE
}
__device__ __forceinline__ void st_wbf(unsigned short* p, float v) {
    __hip_atomic_store(p, f2bf(v), __ATOMIC_RELAXED, AGENT);
}
__device__ __forceinline__ float ld_wbf(const unsigned short* p) {
    unsigned short u = __hip_atomic_load(p, __ATOMIC_RELAXED, AGENT);
    return __uint_as_float(((unsigned int)u) << 16);
}

// ---------------- fp8 helpers (HW cvt or SW fallback) ----------------------
#if !HAVE_FP8_CVT
__device__ __forceinline__ float fp8dec_sw(unsigned int b) {
    unsigned int e = (b >> 3) & 0xFu, m = b & 7u;
    float mag = (e == 0) ? (float)m * 0.001953125f
                         : __uint_as_float(((e + 120u) << 23) | (m << 20));
    return (b & 0x80u) ? -mag : mag;
}
__device__ __forceinline__ unsigned int fp8enc_sw(float v) {
    if (v <= 0.0f) return 0u;
    if (v < 0.015625f) return (unsigned int)rintf(v * 512.0f) & 7u;
    int e; float fr = frexpf(v, &e);
    float q = rintf(fr * 16.0f);
    if (q >= 16.0f) { q = 8.0f; ++e; }
    return (((unsigned int)(e + 6) & 0xFu) << 3) | ((unsigned int)q & 7u);
}
#endif
__device__ __forceinline__ unsigned int pk4_fp8(float e0, float e1, float e2, float e3) {
#if HAVE_FP8_CVT
    int v = __builtin_amdgcn_cvt_pk_fp8_f32(e0, e1, 0, false);
    v = __builtin_amdgcn_cvt_pk_fp8_f32(e2, e3, v, true);
    return (unsigned int)v;
#else
    return fp8enc_sw(e0) | (fp8enc_sw(e1) << 8) | (fp8enc_sw(e2) << 16) | (fp8enc_sw(e3) << 24);
#endif
}
__device__ __forceinline__ void fp8x4_to_f32(unsigned int u, float* f) {
#if HAVE_FP8_CVT
    floatx2 p = __builtin_amdgcn_cvt_pk_f32_fp8((int)u, false);
    f[0] = p.x; f[1] = p.y;
    p = __builtin_amdgcn_cvt_pk_f32_fp8((int)u, true);
    f[2] = p.x; f[3] = p.y;
#else
    f[0] = fp8dec_sw(u & 0xffu);
    f[1] = fp8dec_sw((u >> 8) & 0xffu);
    f[2] = fp8dec_sw((u >> 16) & 0xffu);
    f[3] = fp8dec_sw((u >> 24) & 0xffu);
#endif
}

// ---- fp4 pack: 8 K-values -> one u32 of nibbles (decode-order permuted) ----
__device__ __forceinline__ unsigned int pk8_fp4(const float* e) {
    unsigned int b0 = pk4_fp8(e[0], e[1], e[2], e[3]);
    unsigned int b1 = pk4_fp8(e[4], e[5], e[6], e[7]);
    unsigned int c0 = ((b0 - 0x36363636u) >> 2) & 0x0F0F0F0Fu;
    unsigned int c1 = ((b1 - 0x36363636u) >> 2) & 0x0F0F0F0Fu;
    return c0 | (c1 << 4);
}
__device__ __forceinline__ void fp4x8_to_f32(unsigned int v, float* f) {
    unsigned int blo = ((v << 2) & 0x3C3C3C3Cu) + 0x38383838u;
    unsigned int bhi = ((v >> 2) & 0x3C3C3C3Cu) + 0x38383838u;
    fp8x4_to_f32(blo, f);
    fp8x4_to_f32(bhi, f + 4);
}

// --------------- tree grid barrier (multi-word release) --------------------
__device__ __forceinline__ void gbar(unsigned int* ctrs, unsigned int* rel,
                                     unsigned int phase, int bid, int cpl) {
    __syncthreads();
    if (threadIdx.x == 0) {
        asm volatile("s_waitcnt vmcnt(0)" ::: "memory");
        __hip_atomic_fetch_add(&ctrs[(bid & 63) * 16], 1u, __ATOMIC_RELAXED, AGENT);
    }
    if (bid == 0) {
        if (threadIdx.x < 64) {
            unsigned int tgt = phase * (unsigned int)cpl;
            while (__hip_atomic_load(&ctrs[threadIdx.x * 16], __ATOMIC_RELAXED, AGENT) < tgt)
                __builtin_amdgcn_s_sleep(1);
        }
        __syncthreads();
        if (threadIdx.x < 64)
            __hip_atomic_store(&rel[threadIdx.x * 16], phase, __ATOMIC_RELAXED, AGENT);
    } else if (threadIdx.x == 0) {
        while (__hip_atomic_load(&rel[(bid & 63) * 16], __ATOMIC_RELAXED, AGENT) < phase)
            __builtin_amdgcn_s_sleep(1);
    }
    __syncthreads();
}

// ---- LDS weight slotting: slot(c,q,l) = c*256 + q*64 + l ------------------
__device__ __forceinline__ int slot4(int g8) {
    return ((g8 >> 8) << 8) + (g8 & 3) * 64 + ((g8 >> 2) & 63);
}

// stage wQ (8192 bf16 -> slots [0,1024)) and wP (4096 -> slots [1024,1536))
__device__ __forceinline__ void stage2(const unsigned short* __restrict__ wQ,
                                       const unsigned short* __restrict__ wP,
                                       ull* lds, int tid) {
    uint4* lds4 = (uint4*)lds;
    for (int g8 = tid; g8 < 1024; g8 += BLK) {
        ull v0 = __hip_atomic_load((const ull*)wQ + 2 * g8, __ATOMIC_RELAXED, AGENT);
        ull v1 = __hip_atomic_load((const ull*)wQ + 2 * g8 + 1, __ATOMIC_RELAXED, AGENT);
        lds4[slot4(g8)] = make_uint4((unsigned int)v0, (unsigned int)(v0 >> 32),
                                     (unsigned int)v1, (unsigned int)(v1 >> 32));
    }
    for (int g8 = tid; g8 < 512; g8 += BLK) {
        ull v0 = __hip_atomic_load((const ull*)wP + 2 * g8, __ATOMIC_RELAXED, AGENT);
        ull v1 = __hip_atomic_load((const ull*)wP + 2 * g8 + 1, __ATOMIC_RELAXED, AGENT);
        lds4[1024 + slot4(g8)] = make_uint4((unsigned int)v0, (unsigned int)(v0 >> 32),
                                            (unsigned int)v1, (unsigned int)(v1 >> 32));
    }
    __syncthreads();
}

// fused tiled builder: one 64x64 dist tile -> M1,M2T (row-major) + MT1,MT2 (T)
__device__ __forceinline__ void build_tile4(const float* __restrict__ dist,
                                            const float* __restrict__ rm1,
                                            const float* __restrict__ d12,
                                            unsigned char* __restrict__ M1,
                                            unsigned char* __restrict__ MT1,
                                            unsigned char* __restrict__ M2T,
                                            unsigned char* __restrict__ MT2,
                                            float (*tl)[65], float* rms, float* d12s,
                                            int t, int tid) {
    int i0 = (t >> 7) * 64;
    int j0 = (t & 127) * 64;
    int r = tid >> 2, cq = (tid & 3) * 16;
    {
        const float* Dr = dist + (size_t)(i0 + r) * DC + OFF + j0 + cq;
        float4 v0 = *(const float4*)Dr;
        float4 v1 = *(const float4*)(Dr + 4);
        float4 v2 = *(const float4*)(Dr + 8);
        float4 v3 = *(const float4*)(Dr + 12);
        *(float4*)&tl[r][cq + 0]  = v0;
        *(float4*)&tl[r][cq + 4]  = v1;
        *(float4*)&tl[r][cq + 8]  = v2;
        *(float4*)&tl[r][cq + 12] = v3;
        if (tid < 64) { rms[tid] = rm1[i0 + tid]; d12s[tid] = d12[j0 + tid]; }
    }
    __syncthreads();
    {   // row-major: M1[i][j], M2T[i][j]
        float rm = rms[r];
        int iglob = i0 + r;
        float k1[16], k2[16];
#pragma unroll
        for (int k = 0; k < 16; ++k) {
            int jglob = j0 + cq + k;
            float dvv = tl[r][cq + k];
            bool dg1 = (jglob == iglob) || (jglob == iglob + 4096);
            float g1 = dg1 ? 0.0f : fmaxf(0.05f + dvv - rm, 0.0f);
            k1[k] = __expf(5.0f * __expf(-g1));
            bool dg2 = (iglob == (jglob & 4095));
            float g2 = dg2 ? 0.0f : fmaxf(0.05f + dvv - d12s[cq + k], 0.0f);
            k2[k] = __expf(5.0f * __expf(-g2));
        }
        uint2 o1, o2;
        o1.x = pk8_fp4(k1); o1.y = pk8_fp4(k1 + 8);
        o2.x = pk8_fp4(k2); o2.y = pk8_fp4(k2 + 8);
        *(uint2*)(M1 + (size_t)iglob * 4096 + ((j0 + cq) >> 1)) = o1;
        *(uint2*)(M2T + (size_t)iglob * 4096 + ((j0 + cq) >> 1)) = o2;
    }
    {   // transposed: MT1[j][i], MT2[j][i]
        int jj = r;
        int jglob = j0 + jj;
        float dd = d12s[jj];
        float k1[16], k2[16];
#pragma unroll
        for (int k = 0; k < 16; ++k) {
            int iglob = i0 + cq + k;
            float dvv = tl[cq + k][jj];
            bool dg1 = (jglob == iglob) || (jglob == iglob + 4096);
            float g1 = dg1 ? 0.0f : fmaxf(0.05f + dvv - rms[cq + k], 0.0f);
            k1[k] = __expf(5.0f * __expf(-g1));
            bool dg2 = (iglob == (jglob & 4095));
            float g2 = dg2 ? 0.0f : fmaxf(0.05f + dvv - dd, 0.0f);
            k2[k] = __expf(5.0f * __expf(-g2));
        }
        uint2 o1, o2;
        o1.x = pk8_fp4(k1); o1.y = pk8_fp4(k1 + 8);
        o2.x = pk8_fp4(k2); o2.y = pk8_fp4(k2 + 8);
        *(uint2*)(MT1 + (size_t)jglob * 2048 + ((i0 + cq) >> 1)) = o1;
        *(uint2*)(MT2 + (size_t)jglob * 2048 + ((i0 + cq) >> 1)) = o2;
    }
    __syncthreads();
}

// ------------------------- cooperative dual-loss kernel --------------------
__global__ __launch_bounds__(BLK, 4) void k_main(const float* __restrict__ dist,
                                                 float* __restrict__ out,
                                                 unsigned char* __restrict__ M1,
                                                 unsigned char* __restrict__ MT1,
                                                 unsigned char* __restrict__ M2T,
                                                 unsigned char* __restrict__ MT2,
                                                 unsigned short* __restrict__ w_c1,
                                                 unsigned short* __restrict__ w_c2,
                                                 unsigned short* __restrict__ w_r1,
                                                 unsigned short* __restrict__ w_r2,
                                                 float* __restrict__ rm1,
                                                 int* __restrict__ arg1,
                                                 float* __restrict__ d12,
                                                 float* __restrict__ numb,
                                                 float* __restrict__ denb,
                                                 float* __restrict__ num1,
                                                 float* __restrict__ den1,
                                                 unsigned int* __restrict__ ctrs,
                                                 unsigned int* __restrict__ rel,
                                                 unsigned int* __restrict__ flags) {
    cg::grid_group grid = cg::this_grid();
    const int tid = threadIdx.x, bid = blockIdx.x;
    const int nb = gridDim.x, nt = nb * BLK;
    const int gt = bid * BLK + tid;
    const int nw = nt >> 6, wave = gt >> 6, lane = tid & 63;
    const int cpl = nb >> 6;
    unsigned int pc = 0;

    extern __shared__ char smem[];                // 24832 B
    ull* lds64 = (ull*)smem;
    const uint4* vv4 = (const uint4*)smem;
    float (*tl)[65] = (float(*)[65])smem;
    float* rms  = (float*)(smem + 16640);
    float* d12s = (float*)(smem + 16896);
    // epilogue overlays
    float* wsm  = (float*)smem;                   // 32
    float* rms2 = (float*)(smem + 128);           // 32
    int*  args2 = (int*)(smem + 256);             // 32
    float* n1s  = (float*)(smem + 384);           // 32
    float* d1s  = (float*)(smem + 512);           // 32
    int* chflag = (int*)(smem + 24576);
    int* convfl = (int*)(smem + 24580);

    // ---------------- init ----------------
    for (int t = gt; t < NC; t += nt) {
        if (t == 0) __hip_atomic_store(out, 0.0f, __ATOMIC_RELAXED, AGENT);
        if (t < NR) {
            float a = dist[(size_t)t * DC + OFF + t];
            float b = dist[(size_t)t * DC + OFF + 4096 + t];
            rm1[t] = fmaxf(a, b);
            arg1[t] = (a >= b) ? t : t + 4096;
            st_wbf(&w_r1[t], INV4096);            // u1_0
            __hip_atomic_store(&num1[t], 0.0f, __ATOMIC_RELAXED, AGENT);
            __hip_atomic_store(&den1[t], 0.0f, __ATOMIC_RELAXED, AGENT);
        }
        d12[t] = dist[(size_t)(t & 4095) * DC + OFF + t];
        st_wbf(&w_c2[t], INV8192);                // u2_0
        __hip_atomic_store(&numb[t], 0.0f, __ATOMIC_RELAXED, AGENT);
        __hip_atomic_store(&denb[t], 0.0f, __ATOMIC_RELAXED, AGENT);
    }
    grid.sync();
    for (int t = bid; t < 8192; t += nb)
        build_tile4(dist, rm1, d12, M1, MT1, M2T, MT2, tl, rms, d12s, t, tid);
    grid.sync();

    // ------- interleaved Sinkhorn: <=99 phases, 1-ulp fixed-point exit ------
    // HALF-PARTICIPATION: only blocks bid < nb/2 stage + compute (halves the
    // duplicated weight-staging fabric traffic); others just hit the barrier.
    // Per-row arithmetic and wave->row ownership unchanged -> bit-identical.
    const int halfnb = nb >> 1;
    const bool worker = (bid < halfnb);
    const int wnw = halfnb << 2;                  // working waves
    const int wwv = (bid << 2) | (tid >> 6);      // working wave id (if worker)

    for (int t = 0; t < 99; ++t) {
        bool ph1 = ((t & 1) == 0);
        const unsigned char* P = ph1 ? MT1 : MT2;   // 8192 x 4096 (2048 B rows)
        const unsigned char* Q = ph1 ? M2T : M1;    // 4096 x 8192 (4096 B rows)
        const unsigned short* wPs = ph1 ? w_r1 : w_r2;
        const unsigned short* wQs = ph1 ? w_c2 : w_c1;
        unsigned short* Pout = ph1 ? w_c1 : w_c2;
        unsigned short* Qout = ph1 ? w_r2 : w_r1;
        if (tid == 0) *chflag = 0;
        if (worker) {
            stage2(wQs, wPs, lds64, tid);           // ends with __syncthreads
            for (int r = wwv; r < NR; r += wnw) {
                const unsigned char* qrow = Q + (size_t)r * 4096;
                const unsigned char* p0 = P + (size_t)r * 2048;
                const unsigned char* p1 = P + (size_t)(r + 4096) * 2048;
                // ---- MLP burst: 8 x uint4 global loads ----
                uint4 qa[4], pa[2], pb[2];
#pragma unroll
                for (int c = 0; c < 4; ++c)
                    qa[c] = *(const uint4*)(qrow + c * 1024 + lane * 16);
#pragma unroll
                for (int c = 0; c < 2; ++c) {
                    pa[c] = *(const uint4*)(p0 + c * 1024 + lane * 16);
                    pb[c] = *(const uint4*)(p1 + c * 1024 + lane * 16);
                }
                // ---- Q decode/FMA ----
                float acc = 0.0f;
#pragma unroll
                for (int c = 0; c < 4; ++c) {
                    unsigned int vs[4] = {qa[c].x, qa[c].y, qa[c].z, qa[c].w};
#pragma unroll
                    for (int q = 0; q < 4; ++q) {
                        float f[8];
                        fp4x8_to_f32(vs[q], f);
                        uint4 w = vv4[c * 256 + q * 64 + lane];
                        acc = fmaf(f[0], bflo(w.x), acc); acc = fmaf(f[1], bfhi(w.x), acc);
                        acc = fmaf(f[2], bflo(w.y), acc); acc = fmaf(f[3], bfhi(w.y), acc);
                        acc = fmaf(f[4], bflo(w.z), acc); acc = fmaf(f[5], bfhi(w.z), acc);
                        acc = fmaf(f[6], bflo(w.w), acc); acc = fmaf(f[7], bfhi(w.w), acc);
                    }
                }
                // ---- P pair decode/FMA ----
                float a0 = 0.0f, a1 = 0.0f;
#pragma unroll
                for (int c = 0; c < 2; ++c) {
                    unsigned int va[4] = {pa[c].x, pa[c].y, pa[c].z, pa[c].w};
                    unsigned int vb[4] = {pb[c].x, pb[c].y, pb[c].z, pb[c].w};
#pragma unroll
                    for (int q = 0; q < 4; ++q) {
                        float fa[8], fb[8];
                        fp4x8_to_f32(va[q], fa);
                        fp4x8_to_f32(vb[q], fb);
                        uint4 w = vv4[1024 + c * 256 + q * 64 + lane];
                        float wv[8] = {bflo(w.x), bfhi(w.x), bflo(w.y), bfhi(w.y),
                                       bflo(w.z), bfhi(w.z), bflo(w.w), bfhi(w.w)};
#pragma unroll
                        for (int e = 0; e < 8; ++e) {
                            a0 = fmaf(fa[e], wv[e], a0);
                            a1 = fmaf(fb[e], wv[e], a1);
                        }
                    }
                }
                // ---- fused 3-value wave reduce ----
#pragma unroll
                for (int o = 32; o; o >>= 1) {
                    acc += __shfl_down(acc, o);
                    a0 += __shfl_down(a0, o);
                    a1 += __shfl_down(a1, o);
                }
                if (lane == 0) {
                    unsigned short nq = f2bf(__fdividef(INV4096, acc));
                    unsigned short n0 = f2bf(__fdividef(INV8192, a0));
                    unsigned short n1 = f2bf(__fdividef(INV8192, a1));
                    unsigned short oq = __hip_atomic_load(&Qout[r], __ATOMIC_RELAXED, AGENT);
                    unsigned short o0 = __hip_atomic_load(&Pout[r], __ATOMIC_RELAXED, AGENT);
                    unsigned short o1 = __hip_atomic_load(&Pout[r + 4096], __ATOMIC_RELAXED, AGENT);
                    int dq = (int)nq - (int)oq;
                    int d0i = (int)n0 - (int)o0;
                    int d1i = (int)n1 - (int)o1;
                    if (dq > 1 || dq < -1 || d0i > 1 || d0i < -1 || d1i > 1 || d1i < -1)
                        *chflag = 1;
                    __hip_atomic_store(&Qout[r], nq, __ATOMIC_RELAXED, AGENT);
                    __hip_atomic_store(&Pout[r], n0, __ATOMIC_RELAXED, AGENT);
                    __hip_atomic_store(&Pout[r + 4096], n1, __ATOMIC_RELAXED, AGENT);
                }
            }
        }
        __syncthreads();
        if (tid == 0 && *chflag)
            __hip_atomic_store(&flags[t], 1u, __ATOMIC_RELAXED, AGENT);  // before arrival
        gbar(ctrs, rel, ++pc, bid, cpl);
        if (tid == 0)
            *convfl = (int)__hip_atomic_load(&flags[t], __ATOMIC_RELAXED, AGENT);
        __syncthreads();
        if (*convfl == 0) break;                    // <=1-ulp fixed point: stop
    }

    // ---------------- fused epilogue: one dist pass, both losses ----------
    for (int t2 = bid; t2 < 1024; t2 += nb) {
        int r0 = (t2 >> 3) * 32;
        int c = (t2 & 7) * 1024 + tid * 4;
        if (tid < 32) {
            wsm[tid]  = ld_wbf(&w_r2[r0 + tid]);
            rms2[tid] = rm1[r0 + tid];
            args2[tid] = arg1[r0 + tid];
            n1s[tid] = 0.0f; d1s[tid] = 0.0f;
        }
        __syncthreads();
        ull wcu = __hip_atomic_load((const ull*)w_c1 + (c >> 2), __ATOMIC_RELAXED, AGENT);
        float wc1v[4] = {bfs((unsigned short)wcu), bfs((unsigned short)(wcu >> 16)),
                         bfs((unsigned short)(wcu >> 32)), bfs((unsigned short)(wcu >> 48))};
        float4 e0 = *(const float4*)(d12 + c);
        float dd[4] = {e0.x, e0.y, e0.z, e0.w};
        float nacc2[4] = {0.f, 0.f, 0.f, 0.f};
        float dacc2[4] = {0.f, 0.f, 0.f, 0.f};
        for (int r = 0; r < 32; ++r) {
            int rr = r0 + r;
            float rm = rms2[r];
            int arg = args2[r];
            float ww = wsm[r];
            float4 dv4 = *(const float4*)(dist + (size_t)rr * DC + OFF + c);
            float dv[4] = {dv4.x, dv4.y, dv4.z, dv4.w};
            float n1t = 0.0f, d1t = 0.0f;
#pragma unroll
            for (int e = 0; e < 4; ++e) {
                int cc = c + e;
                float d = dv[e];
                float gm2 = fmaxf(0.05f + d - dd[e], 0.0f);
                float K2 = __expf(5.0f * __expf(-gm2));
                float wv2 = (rr == (cc & 4095)) ? 0.0f : K2 * ww;
                nacc2[e] += wv2 * gm2;
                dacc2[e] += wv2;
                bool isd1 = (cc == rr) || (cc == rr + 4096);
                float goff = fmaxf(0.05f + d - rm, 0.0f);
                float K1 = __expf(5.0f * __expf(-(isd1 ? 0.0f : goff)));
                float gm1 = isd1 ? fmaxf(rm - 0.5f - d, 0.0f) : goff;
                bool keep = (cc != arg) && ((cc < 4096) || (cc == rr + 4096));
                float wv1 = keep ? K1 * wc1v[e] : 0.0f;
                n1t += wv1 * gm1;
                d1t += wv1;
            }
#pragma unroll
            for (int o = 32; o; o >>= 1) {
                n1t += __shfl_down(n1t, o);
                d1t += __shfl_down(d1t, o);
            }
            if (lane == 0) {
                atomicAdd(&n1s[r], n1t);
                atomicAdd(&d1s[r], d1t);
            }
        }
        __syncthreads();
#pragma unroll
        for (int e = 0; e < 4; ++e) {
            atomicAdd(&numb[c + e], nacc2[e]);
            atomicAdd(&denb[c + e], dacc2[e]);
        }
        if (tid < 32) {
            atomicAdd(&num1[r0 + tid], n1s[tid]);
            atomicAdd(&den1[r0 + tid], d1s[tid]);
        }
        __syncthreads();
    }
    gbar(ctrs, rel, ++pc, bid, cpl);

    // ---------------- final reduce: loss2 (128 groups) + loss1 (64 groups) --
    for (int t2 = wave; t2 < 192; t2 += nw) {
        float v;
        if (t2 < 128) {
            int cc = t2 * 64 + lane;
            float n = __hip_atomic_load(&numb[cc], __ATOMIC_RELAXED, AGENT);
            float dn = __hip_atomic_load(&denb[cc], __ATOMIC_RELAXED, AGENT);
            v = n / dn;
        } else {
            int ii = (t2 - 128) * 64 + lane;
            float n = __hip_atomic_load(&num1[ii], __ATOMIC_RELAXED, AGENT);
            float dn = __hip_atomic_load(&den1[ii], __ATOMIC_RELAXED, AGENT);
            v = n / dn;
        }
#pragma unroll
        for (int o = 32; o; o >>= 1) v += __shfl_down(v, o);
        if (lane == 0) atomicAdd(out, v);
    }
}

// ------------------------- fallback multi-kernel path (bf16, proven) -------
__device__ __forceinline__ void fb_build1(const float* __restrict__ dist,
                                          const float* __restrict__ rm1,
                                          unsigned short* __restrict__ M, int c) {
    int i = c >> 10;
    int j = (c & 1023) << 3;
    float rm = rm1[i];
    const float* Dr = dist + (size_t)i * DC + OFF + j;
    float4 d0 = *(const float4*)Dr;
    float4 d1 = *(const float4*)(Dr + 4);
    float dv[8] = {d0.x, d0.y, d0.z, d0.w, d1.x, d1.y, d1.z, d1.w};
    unsigned short e[8];
#pragma unroll
    for (int k = 0; k < 8; ++k) {
        int jj = j + k;
        bool diag = (jj == i) || (jj == i + 4096);
        float gm = diag ? 0.0f : fmaxf(0.05f + dv[k] - rm, 0.0f);
        e[k] = f2bf(__expf(5.0f * __expf(-gm)));
    }
    uint4 o;
    o.x = (unsigned int)e[0] | ((unsigned int)e[1] << 16);
    o.y = (unsigned int)e[2] | ((unsigned int)e[3] << 16);
    o.z = (unsigned int)e[4] | ((unsigned int)e[5] << 16);
    o.w = (unsigned int)e[6] | ((unsigned int)e[7] << 16);
    *(uint4*)(M + (size_t)c * 8) = o;
}
__device__ __forceinline__ void fb_build2(const float* __restrict__ dist,
                                          const float* __restrict__ d12,
                                          unsigned short* __restrict__ M, int c) {
    int r = c >> 10;
    int col = (c & 1023) << 3;
    const float* Dr = dist + (size_t)r * DC + OFF + col;
    float4 d0 = *(const float4*)Dr;
    float4 d1 = *(const float4*)(Dr + 4);
    float4 e0 = *(const float4*)(d12 + col);
    float4 e1 = *(const float4*)(d12 + col + 4);
    float dv[8] = {d0.x, d0.y, d0.z, d0.w, d1.x, d1.y, d1.z, d1.w};
    float dd[8] = {e0.x, e0.y, e0.z, e0.w, e1.x, e1.y, e1.z, e1.w};
    unsigned short e[8];
#pragma unroll
    for (int k = 0; k < 8; ++k) {
        int cc = col + k;
        bool diag = (r == (cc & 4095));
        float gm = diag ? 0.0f : fmaxf(0.05f + dv[k] - dd[k], 0.0f);
        e[k] = f2bf(__expf(5.0f * __expf(-gm)));
    }
    uint4 o;
    o.x = (unsigned int)e[0] | ((unsigned int)e[1] << 16);
    o.y = (unsigned int)e[2] | ((unsigned int)e[3] << 16);
    o.z = (unsigned int)e[4] | ((unsigned int)e[5] << 16);
    o.w = (unsigned int)e[6] | ((unsigned int)e[7] << 16);
    *(uint4*)(M + (size_t)c * 8) = o;
}
__device__ __forceinline__ void fb_transpose(const unsigned short* __restrict__ M,
                                             unsigned short* __restrict__ MT,
                                             unsigned int (*tile)[33], int t, int tid) {
    int r0 = (t >> 7) * 64;
    int c0 = (t & 127) * 64;
    int lc = tid & 7, rr = tid >> 3;
#pragma unroll
    for (int s = 0; s < 2; ++s) {
        int r = rr + s * 32;
        uint4 a = *(const uint4*)(M + (size_t)(r0 + r) * NC + c0 + lc * 8);
        tile[r][lc * 4 + 0] = a.x;
        tile[r][lc * 4 + 1] = a.y;
        tile[r][lc * 4 + 2] = a.z;
        tile[r][lc * 4 + 3] = a.w;
    }
    __syncthreads();
    int cc = tid >> 2, rs = (tid & 3) * 16;
    unsigned int o[8];
#pragma unroll
    for (int w = 0; w < 8; ++w) {
        unsigned int ue = tile[rs + 2 * w][cc >> 1];
        unsigned int uo = tile[rs + 2 * w + 1][cc >> 1];
        unsigned short e = (cc & 1) ? (unsigned short)(ue >> 16) : (unsigned short)(ue & 0xffffu);
        unsigned short d = (cc & 1) ? (unsigned short)(uo >> 16) : (unsigned short)(uo & 0xffffu);
        o[w] = (unsigned int)e | ((unsigned int)d << 16);
    }
    unsigned short* dst = MT + (size_t)(c0 + cc) * NR + r0 + rs;
    *(uint4*)dst = make_uint4(o[0], o[1], o[2], o[3]);
    *(uint4*)(dst + 8) = make_uint4(o[4], o[5], o[6], o[7]);
    __syncthreads();
}
template <int W>
__device__ __forceinline__ float rowdot_g(const unsigned short* __restrict__ row,
                                          const float* __restrict__ w, int lane) {
    float acc = 0.0f;
#pragma unroll
    for (int s = 0; s < W; s += 512) {
        int j = s + lane * 8;
        uint4 a = *(const uint4*)(row + j);
        float4 w0 = *(const float4*)(w + j);
        float4 w1 = *(const float4*)(w + j + 4);
        acc = fmaf(bflo(a.x), w0.x, acc);
        acc = fmaf(bfhi(a.x), w0.y, acc);
        acc = fmaf(bflo(a.y), w0.z, acc);
        acc = fmaf(bfhi(a.y), w0.w, acc);
        acc = fmaf(bflo(a.z), w1.x, acc);
        acc = fmaf(bfhi(a.z), w1.y, acc);
        acc = fmaf(bflo(a.w), w1.z, acc);
        acc = fmaf(bfhi(a.w), w1.w, acc);
    }
#pragma unroll
    for (int o = 32; o; o >>= 1) acc += __shfl_down(acc, o);
    return acc;
}
__global__ __launch_bounds__(BLK) void k_fb_init(const float* __restrict__ dist,
                                                 float* __restrict__ rm1, int* __restrict__ arg1,
                                                 float* __restrict__ d12, float* __restrict__ wrow,
                                                 float* __restrict__ out) {
    int t = blockIdx.x * BLK + threadIdx.x;
    if (t == 0) out[0] = 0.0f;
    if (t < NR) {
        float a = dist[(size_t)t * DC + OFF + t];
        float b = dist[(size_t)t * DC + OFF + 4096 + t];
        rm1[t] = fmaxf(a, b);
        arg1[t] = (a >= b) ? t : t + 4096;
        wrow[t] = INV4096;
    }
    d12[t] = dist[(size_t)(t & 4095) * DC + OFF + t];
}
__global__ __launch_bounds__(BLK) void k_fb_build1(const float* __restrict__ dist,
                                                   const float* __restrict__ rm1,
                                                   unsigned short* __restrict__ M) {
    fb_build1(dist, rm1, M, blockIdx.x * BLK + threadIdx.x);
}
__global__ __launch_bounds__(BLK) void k_fb_build2(const float* __restrict__ dist,
                                                   const float* __restrict__ d12,
                                                   unsigned short* __restrict__ M) {
    fb_build2(dist, d12, M, blockIdx.x * BLK + threadIdx.x);
}
__global__ __launch_bounds__(BLK) void k_fb_transp(const unsigned short* __restrict__ M,
                                                   unsigned short* __restrict__ MT) {
    __shared__ unsigned int tile[64][33];
    fb_transpose(M, MT, tile, blockIdx.x, threadIdx.x);
}
template <int W>
__global__ __launch_bounds__(BLK) void k_fb_matvec(const unsigned short* __restrict__ Mat,
                                                   const float* __restrict__ w,
                                                   float* __restrict__ outv, float scale) {
    int r = blockIdx.x * 4 + (threadIdx.x >> 6);
    float s = rowdot_g<W>(Mat + (size_t)r * W, w, threadIdx.x & 63);
    if ((threadIdx.x & 63) == 0) outv[r] = __fdividef(scale, s);
}
__global__ __launch_bounds__(BLK) void k_fb_epi1(const unsigned short* __restrict__ M,
                                                 const float* __restrict__ dist,
                                                 const float* __restrict__ wcol,
                                                 const float* __restrict__ rm1,
                                                 const int* __restrict__ arg1,
                                                 float* __restrict__ out) {
    int i = blockIdx.x * 4 + (threadIdx.x >> 6);
    int lane = threadIdx.x & 63;
    float rm = rm1[i];
    int arg = arg1[i];
    const unsigned short* Ar = M + (size_t)i * NC;
    const float* Dr = dist + (size_t)i * DC + OFF;
    float num = 0.0f, den = 0.0f;
#pragma unroll 4
    for (int s = 0; s < NC; s += 512) {
        int j0 = s + lane * 8;
        uint4 a = *(const uint4*)(Ar + j0);
        float4 t0 = *(const float4*)(wcol + j0);
        float4 t1 = *(const float4*)(wcol + j0 + 4);
        float4 d0 = *(const float4*)(Dr + j0);
        float4 d1 = *(const float4*)(Dr + j0 + 4);
        float av[8] = {bflo(a.x), bfhi(a.x), bflo(a.y), bfhi(a.y),
                       bflo(a.z), bfhi(a.z), bflo(a.w), bfhi(a.w)};
        float tv[8] = {t0.x, t0.y, t0.z, t0.w, t1.x, t1.y, t1.z, t1.w};
        float dv[8] = {d0.x, d0.y, d0.z, d0.w, d1.x, d1.y, d1.z, d1.w};
#pragma unroll
        for (int e = 0; e < 8; ++e) {
            int jj = j0 + e;
            bool isdiag = (jj == i) || (jj == i + 4096);
            float gm = isdiag ? fmaxf(rm - 0.5f - dv[e], 0.0f)
                              : fmaxf(0.05f + dv[e] - rm, 0.0f);
            bool keep = (jj != arg) && ((jj < 4096) || (jj == i + 4096));
            float wv = keep ? av[e] * tv[e] : 0.0f;
            num += wv * gm;
            den += wv;
        }
    }
#pragma unroll
    for (int o = 32; o; o >>= 1) {
        num += __shfl_down(num, o);
        den += __shfl_down(den, o);
    }
    if (lane == 0) atomicAdd(out, num / den);
}
__global__ __launch_bounds__(BLK) void k_fb_init2(float* __restrict__ wcol,
                                                  float* __restrict__ numb,
                                                  float* __restrict__ denb) {
    int t = blockIdx.x * BLK + threadIdx.x;
    wcol[t] = INV8192;
    numb[t] = 0.0f;
    denb[t] = 0.0f;
}
__global__ __launch_bounds__(BLK) void k_fb_epi2(const unsigned short* __restrict__ M,
                                                 const float* __restrict__ dist,
                                                 const float* __restrict__ wrow,
                                                 const float* __restrict__ d12,
                                                 float* __restrict__ numb,
                                                 float* __restrict__ denb) {
    __shared__ float wsm[64];
    int t = blockIdx.x, tid = threadIdx.x;
    int r0 = (t >> 3) * 64;
    int c = (t & 7) * 1024 + tid * 4;
    if (tid < 64) wsm[tid] = wrow[r0 + tid];
    __syncthreads();
    float4 e0 = *(const float4*)(d12 + c);
    float dd[4] = {e0.x, e0.y, e0.z, e0.w};
    float nacc[4] = {0.f, 0.f, 0.f, 0.f};
    float dacc[4] = {0.f, 0.f, 0.f, 0.f};
    for (int r = 0; r < 64; ++r) {
        int rr = r0 + r;
        uint2 a = *(const uint2*)(M + (size_t)rr * NC + c);
        float4 dv4 = *(const float4*)(dist + (size_t)rr * DC + OFF + c);
        float av[4] = {bflo(a.x), bfhi(a.x), bflo(a.y), bfhi(a.y)};
        float dv[4] = {dv4.x, dv4.y, dv4.z, dv4.w};
        float ww = wsm[r];
#pragma unroll
        for (int e = 0; e < 4; ++e) {
            int cc = c + e;
            bool isdiag = (rr == (cc & 4095));
            float gm = fmaxf(0.05f + dv[e] - dd[e], 0.0f);
            float wv = isdiag ? 0.0f : av[e] * ww;
            nacc[e] += wv * gm;
            dacc[e] += wv;
        }
    }
#pragma unroll
    for (int e = 0; e < 4; ++e) {
        atomicAdd(&numb[c + e], nacc[e]);
        atomicAdd(&denb[c + e], dacc[e]);
    }
}
__global__ __launch_bounds__(BLK) void k_fb_epi2fin(const float* __restrict__ numb,
                                                    const float* __restrict__ denb,
                                                    float* __restrict__ out) {
    int c = blockIdx.x * BLK + threadIdx.x;
    float v = numb[c] / denb[c];
    __shared__ float sm[4];
#pragma unroll
    for (int o = 32; o; o >>= 1) v += __shfl_down(v, o);
    if ((threadIdx.x & 63) == 0) sm[threadIdx.x >> 6] = v;
    __syncthreads();
    if (threadIdx.x == 0) atomicAdd(out, sm[0] + sm[1] + sm[2] + sm[3]);
}

// ---------------------------------------------------------------------------
extern "C" void kernel_launch(void* const* d_in, const int* in_sizes, int n_in,
                              void* d_out, int out_size, void* d_ws, size_t ws_size,
                              hipStream_t stream) {
    const float* dist = (const float*)d_in[0];
    float* out = (float*)d_out;

    const size_t MB32 = (size_t)NR * NC;          // elems per matrix
    const size_t MB4  = MB32 / 2;                 // fp4 bytes per matrix
    unsigned char* M1  = (unsigned char*)d_ws;
    unsigned char* MT1 = M1 + MB4;
    unsigned char* M2T = MT1 + MB4;
    unsigned char* MT2 = M2T + MB4;               // 67 MB total (L3-resident)
    unsigned short* Mfb  = (unsigned short*)d_ws; // fallback overlay
    unsigned short* MTfb = Mfb + MB32;
    // aux beyond 134 MB
    unsigned short* w_c1 = (unsigned short*)((char*)d_ws + 4 * MB32);
    unsigned short* w_c2 = w_c1 + NC;
    unsigned short* w_r1 = w_c2 + NC;
    unsigned short* w_r2 = w_r1 + NR;
    float* fbf   = (float*)(w_r2 + NR);
    float* wrowF = fbf;
    float* wcolF = wrowF + NR;
    float* rm1  = wcolF + NC;
    int*   arg1 = (int*)(rm1 + NR);
    float* d12  = (float*)(arg1 + NR);
    float* numb = d12 + NC;
    float* denb = numb + NC;
    float* num1 = denb + NC;
    float* den1 = num1 + NR;
    unsigned int* ctrs  = (unsigned int*)(den1 + NR);  // 64*16
    unsigned int* rel   = ctrs + 64 * 16;              // 64*16
    unsigned int* flags = rel + 64 * 16;               // 128

    const unsigned int SMEM = 24832;

    int dev = 0;
    (void)hipGetDevice(&dev);
    int numCU = 0;
    (void)hipDeviceGetAttribute(&numCU, hipDeviceAttributeMultiprocessorCount, dev);
    int maxPerCU = 0;
    (void)hipOccupancyMaxActiveBlocksPerMultiprocessor(&maxPerCU, (const void*)k_main,
                                                       BLK, SMEM);
    hipError_t rc = hipErrorUnknown;
    int cand = (numCU > 0 && maxPerCU > 0) ? maxPerCU * numCU : 0;
    if (cand > 1024) cand = 1024;
    int grid = 0;
    if (cand >= 128) { grid = 128; while (grid * 2 <= cand) grid *= 2; }
    if (grid > 0) {
        (void)hipMemsetAsync(ctrs, 0, (64 * 16 * 2 + 128) * sizeof(unsigned int), stream);
        void* args[] = {(void*)&dist, (void*)&out, (void*)&M1, (void*)&MT1,
                        (void*)&M2T, (void*)&MT2,
                        (void*)&w_c1, (void*)&w_c2, (void*)&w_r1, (void*)&w_r2,
                        (void*)&rm1, (void*)&arg1, (void*)&d12,
                        (void*)&numb, (void*)&denb, (void*)&num1, (void*)&den1,
                        (void*)&ctrs, (void*)&rel, (void*)&flags};
        for (int g = grid; g >= 128 && rc != hipSuccess; g >>= 1) {
            rc = hipLaunchCooperativeKernel((void*)k_main, dim3(g), dim3(BLK),
                                            args, SMEM, stream);
            if (rc != hipSuccess) (void)hipGetLastError();
        }
    }
    if (rc == hipSuccess) return;

    // ---- fallback: multi-kernel graph path (guaranteed) ----
    k_fb_init<<<32, BLK, 0, stream>>>(dist, rm1, arg1, d12, wrowF, out);
    k_fb_build1<<<16384, BLK, 0, stream>>>(dist, rm1, Mfb);
    k_fb_transp<<<8192, BLK, 0, stream>>>(Mfb, MTfb);
    for (int it = 0; it < 50; ++it) {
        k_fb_matvec<NR><<<2048, BLK, 0, stream>>>(MTfb, wrowF, wcolF, INV8192);
        if (it == 49) break;
        k_fb_matvec<NC><<<1024, BLK, 0, stream>>>(Mfb, wcolF, wrowF, INV4096);
    }
    k_fb_epi1<<<1024, BLK, 0, stream>>>(Mfb, dist, wcolF, rm1, arg1, out);

    k_fb_build2<<<16384, BLK, 0, stream>>>(dist, d12, Mfb);
    k_fb_init2<<<32, BLK, 0, stream>>>(wcolF, numb, denb);
    k_fb_transp<<<8192, BLK, 0, stream>>>(Mfb, MTfb);
    for (int it = 0; it < 50; ++it) {
        k_fb_matvec<NC><<<1024, BLK, 0, stream>>>(Mfb, wcolF, wrowF, INV4096);
        if (it == 49) break;
        k_fb_matvec<NR><<<2048, BLK, 0, stream>>>(MTfb, wrowF, wcolF, INV8192);
    }
    k_fb_epi2<<<512, BLK, 0, stream>>>(Mfb, dist, wrowF, d12, numb, denb);
    k_fb_epi2fin<<<32, BLK, 0, stream>>>(numb, denb, out);
}